// Round 1
// baseline (1073.670 us; speedup 1.0000x reference)
//
#include <hip/hip_runtime.h>
#include <cstdint>
#include <cstddef>

#define TOK     8192
#define DIMD    1024
#define INTERD  1024
#define NEXP    16
#define SINTER  2048
#define CAPROWS 34816   // 32768 + 16*128 padding capacity
#define MAXTILES 272    // sum ceil(cnt_e/128) <= 256 + 16

typedef __bf16 bf16_t;
typedef __bf16 bf16x8_t __attribute__((ext_vector_type(8)));
typedef __bf16 bf16x4_t __attribute__((ext_vector_type(4)));
typedef float  f32x4_t  __attribute__((ext_vector_type(4)));

// async global->LDS, 16B per lane; LDS dest is wave-uniform base + lane*16
__device__ __forceinline__ void gload_lds16(const bf16_t* g, bf16_t* l) {
  __builtin_amdgcn_global_load_lds((const __attribute__((address_space(1))) void*)g,
                                   (__attribute__((address_space(3))) void*)l,
                                   16, 0, 0);
}

// ---------------- init: zero counts/cursors, pad lists ----------------
__global__ void init_kernel(int* toklist, float* wtlist, int* counts, int* cursors,
                            int* tile_e, int* tile_rs) {
  int i = blockIdx.x * blockDim.x + threadIdx.x;
  if (i < CAPROWS) { toklist[i] = -1; wtlist[i] = 0.0f; }
  if (i < NEXP)    { counts[i] = 0; cursors[i] = 0; }
  if (i < 512)     { tile_e[i] = -1; tile_rs[i] = 0; }
}

// ---------------- fp32 -> bf16 conversion ----------------
__global__ void cvt_kernel(const float* __restrict__ in, bf16_t* __restrict__ out, int n4) {
  int stride = gridDim.x * blockDim.x;
  for (int i = blockIdx.x * blockDim.x + threadIdx.x; i < n4; i += stride) {
    float4 v = ((const float4*)in)[i];
    bf16x4_t o;
    o[0] = (bf16_t)v.x; o[1] = (bf16_t)v.y; o[2] = (bf16_t)v.z; o[3] = (bf16_t)v.w;
    ((bf16x4_t*)out)[i] = o;
  }
}

// ---------------- gate: scores -> softmax -> top4 (fp32, one wave/token) ----------------
__global__ __launch_bounds__(256)
void gate_kernel(const float* __restrict__ x, const float* __restrict__ gw,
                 int* __restrict__ tkidx, float* __restrict__ tkwt, int* __restrict__ counts) {
  int wv = threadIdx.x >> 6, lane = threadIdx.x & 63;
  int t = blockIdx.x * 4 + wv;
  const float4* xp = (const float4*)(x + (size_t)t * DIMD + lane * 16);
  float4 xv[4];
#pragma unroll
  for (int i = 0; i < 4; ++i) xv[i] = xp[i];
  float sc[NEXP];
#pragma unroll
  for (int e = 0; e < NEXP; ++e) {
    const float4* wp = (const float4*)(gw + (size_t)e * DIMD + lane * 16);
    float s = 0.0f;
#pragma unroll
    for (int i = 0; i < 4; ++i) {
      float4 w = wp[i];
      s += xv[i].x * w.x + xv[i].y * w.y + xv[i].z * w.z + xv[i].w * w.w;
    }
    sc[e] = s;
  }
#pragma unroll
  for (int off = 32; off > 0; off >>= 1)
#pragma unroll
    for (int e = 0; e < NEXP; ++e)
      sc[e] += __shfl_xor(sc[e], off, 64);
  if (lane == 0) {
    float m = sc[0];
#pragma unroll
    for (int e = 1; e < NEXP; ++e) m = fmaxf(m, sc[e]);
    float p[NEXP], s = 0.0f;
#pragma unroll
    for (int e = 0; e < NEXP; ++e) { p[e] = __expf(sc[e] - m); s += p[e]; }
    float inv = 1.0f / s;
    unsigned used = 0;
    for (int k = 0; k < 4; ++k) {
      int best = 0; float bv = -1.0f;
#pragma unroll
      for (int e = 0; e < NEXP; ++e)
        if (!((used >> e) & 1u) && p[e] > bv) { bv = p[e]; best = e; }
      used |= 1u << best;
      tkidx[t * 4 + k] = best;
      tkwt[t * 4 + k] = bv * inv;
      atomicAdd(&counts[best], 1);
    }
  }
}

// ---------------- offsets + tile table (single thread, 16 experts) ----------------
__global__ void offs_kernel(const int* __restrict__ counts, int* __restrict__ offsets,
                            int* __restrict__ tile_e, int* __restrict__ tile_rs) {
  if (threadIdx.x != 0 || blockIdx.x != 0) return;
  int off = 0, nt = 0;
  for (int e = 0; e < NEXP; ++e) {
    offsets[e] = off;
    int c = counts[e];
    int ntile = (c + 127) >> 7;
    for (int i = 0; i < ntile; ++i) { tile_e[nt] = e; tile_rs[nt] = off + (i << 7); ++nt; }
    off += ntile << 7;
  }
  offsets[NEXP] = off;
}

// ---------------- scatter tokens into per-expert lists ----------------
__global__ void scat_kernel(const int* __restrict__ tkidx, const float* __restrict__ tkwt,
                            const int* __restrict__ offsets, int* __restrict__ cursors,
                            int* __restrict__ toklist, float* __restrict__ wtlist) {
  int i = blockIdx.x * blockDim.x + threadIdx.x;
  if (i >= TOK * 4) return;
  int t = i >> 2;
  int e = tkidx[i];
  float w = tkwt[i];
  int pos = atomicAdd(&cursors[e], 1);
  int dst = offsets[e] + pos;
  toklist[dst] = t;
  wtlist[dst] = w;
}

// ---------------- dual GEMM1: H = silu(X*W1^T+b1)*(X*W3^T+b3)*wt ----------------
// 128x128 tile, BK=32, 4 waves each 64x64 (4x4 frags), global_load_lds staging.
template <bool GATHER>
__global__ __launch_bounds__(256, 2)
void ffn_gemm1(const bf16_t* __restrict__ Xb,
               const bf16_t* __restrict__ W1b, const bf16_t* __restrict__ W3b,
               const float* __restrict__ B1b, const float* __restrict__ B3b,
               bf16_t* __restrict__ H,
               const int* __restrict__ tile_e, const int* __restrict__ tile_rs,
               const int* __restrict__ toklist, const float* __restrict__ wtlist,
               int Ncols) {
  __shared__ __align__(16) bf16_t lA[128 * 32];
  __shared__ __align__(16) bf16_t lB1[128 * 32];
  __shared__ __align__(16) bf16_t lB3[128 * 32];

  int rowstart;
  const bf16_t *W1, *W3;
  const float *b1p, *b3p;
  if constexpr (GATHER) {
    int e = tile_e[blockIdx.y];
    if (e < 0) return;
    rowstart = tile_rs[blockIdx.y];
    W1 = W1b + (size_t)e * INTERD * DIMD;
    W3 = W3b + (size_t)e * INTERD * DIMD;
    b1p = B1b + e * INTERD;
    b3p = B3b + e * INTERD;
  } else {
    rowstart = blockIdx.y * 128;
    W1 = W1b; W3 = W3b; b1p = B1b; b3p = B3b;
  }
  int col0 = blockIdx.x * 128;
  int tid = threadIdx.x, lane = tid & 63, wv = tid >> 6;
  int wm = wv >> 1, wn = wv & 1;

  // staging: chunk c covers LDS bytes [c*16,+16) = row c>>2, k-elems [(c&3)*8,+8)
  int r0 = tid >> 2, r1 = r0 + 64, kc = (tid & 3) * 8;
  int tA0, tA1;
  if constexpr (GATHER) {
    tA0 = toklist[rowstart + r0]; if (tA0 < 0) tA0 = 0;
    tA1 = toklist[rowstart + r1]; if (tA1 < 0) tA1 = 0;
  } else { tA0 = rowstart + r0; tA1 = rowstart + r1; }
  const bf16_t* gA0 = Xb + (size_t)tA0 * DIMD + kc;
  const bf16_t* gA1 = Xb + (size_t)tA1 * DIMD + kc;
  const bf16_t* gB10 = W1 + (size_t)(col0 + r0) * DIMD + kc;
  const bf16_t* gB11 = W1 + (size_t)(col0 + r1) * DIMD + kc;
  const bf16_t* gB30 = W3 + (size_t)(col0 + r0) * DIMD + kc;
  const bf16_t* gB31 = W3 + (size_t)(col0 + r1) * DIMD + kc;
  bf16_t* lA0 = lA + (wv * 64) * 8;        bf16_t* lA1 = lA + (256 + wv * 64) * 8;
  bf16_t* lB10 = lB1 + (wv * 64) * 8;      bf16_t* lB11 = lB1 + (256 + wv * 64) * 8;
  bf16_t* lB30 = lB3 + (wv * 64) * 8;      bf16_t* lB31 = lB3 + (256 + wv * 64) * 8;

  f32x4_t acc1[4][4] = {};
  f32x4_t acc3[4][4] = {};

  int mrow = wm * 64 + (lane & 15);
  int ncol = wn * 64 + (lane & 15);
  int koff = (lane >> 4) * 8;

  for (int k0 = 0; k0 < DIMD; k0 += 32) {
    gload_lds16(gA0 + k0, lA0);
    gload_lds16(gA1 + k0, lA1);
    gload_lds16(gB10 + k0, lB10);
    gload_lds16(gB11 + k0, lB11);
    gload_lds16(gB30 + k0, lB30);
    gload_lds16(gB31 + k0, lB31);
    __syncthreads();
    bf16x8_t af[4], b1f[4], b3f[4];
#pragma unroll
    for (int i = 0; i < 4; ++i) {
      af[i]  = *(const bf16x8_t*)&lA [(mrow + i * 16) * 32 + koff];
      b1f[i] = *(const bf16x8_t*)&lB1[(ncol + i * 16) * 32 + koff];
      b3f[i] = *(const bf16x8_t*)&lB3[(ncol + i * 16) * 32 + koff];
    }
#pragma unroll
    for (int mi = 0; mi < 4; ++mi)
#pragma unroll
      for (int ni = 0; ni < 4; ++ni) {
        acc1[mi][ni] = __builtin_amdgcn_mfma_f32_16x16x32_bf16(af[mi], b1f[ni], acc1[mi][ni], 0, 0, 0);
        acc3[mi][ni] = __builtin_amdgcn_mfma_f32_16x16x32_bf16(af[mi], b3f[ni], acc3[mi][ni], 0, 0, 0);
      }
    __syncthreads();
  }

  float bias1[4], bias3[4];
#pragma unroll
  for (int ni = 0; ni < 4; ++ni) {
    int cg = col0 + wn * 64 + ni * 16 + (lane & 15);
    bias1[ni] = b1p[cg];
    bias3[ni] = b3p[cg];
  }
#pragma unroll
  for (int mi = 0; mi < 4; ++mi)
#pragma unroll
    for (int rg = 0; rg < 4; ++rg) {
      int rl = wm * 64 + mi * 16 + ((lane >> 4) << 2) + rg;  // C/D: row=(lane>>4)*4+reg
      int grow = rowstart + rl;
      float wt = 1.0f;
      if constexpr (GATHER) wt = wtlist[grow];
      size_t hbase = (size_t)grow * Ncols + col0 + wn * 64 + (lane & 15);
#pragma unroll
      for (int ni = 0; ni < 4; ++ni) {
        float v1 = acc1[mi][ni][rg] + bias1[ni];
        float v3 = acc3[mi][ni][rg] + bias3[ni];
        float sg = v1 / (1.0f + __expf(-v1));
        H[hbase + ni * 16] = (bf16_t)(sg * v3 * wt);
      }
    }
}

// ---------------- GEMM2: out = H*W2^T (+ wt*b2 scatter-add | + b2 write) ----------------
template <bool SCATTER>
__global__ __launch_bounds__(256, 2)
void ffn_gemm2(const bf16_t* __restrict__ Hin, const bf16_t* __restrict__ W2b,
               const float* __restrict__ B2b, float* __restrict__ Out,
               const int* __restrict__ tile_e, const int* __restrict__ tile_rs,
               const int* __restrict__ toklist, const float* __restrict__ wtlist,
               int Kdim) {
  __shared__ __align__(16) bf16_t lA[128 * 32];
  __shared__ __align__(16) bf16_t lB[128 * 32];

  int rowstart;
  const bf16_t* W2;
  const float* b2p;
  if constexpr (SCATTER) {
    int e = tile_e[blockIdx.y];
    if (e < 0) return;
    rowstart = tile_rs[blockIdx.y];
    W2 = W2b + (size_t)e * DIMD * INTERD;
    b2p = B2b + e * DIMD;
  } else {
    rowstart = blockIdx.y * 128;
    W2 = W2b; b2p = B2b;
  }
  int col0 = blockIdx.x * 128;
  int tid = threadIdx.x, lane = tid & 63, wv = tid >> 6;
  int wm = wv >> 1, wn = wv & 1;

  int r0 = tid >> 2, r1 = r0 + 64, kc = (tid & 3) * 8;
  const bf16_t* gA0 = Hin + (size_t)(rowstart + r0) * Kdim + kc;
  const bf16_t* gA1 = Hin + (size_t)(rowstart + r1) * Kdim + kc;
  const bf16_t* gB0 = W2 + (size_t)(col0 + r0) * Kdim + kc;
  const bf16_t* gB1 = W2 + (size_t)(col0 + r1) * Kdim + kc;
  bf16_t* lA0 = lA + (wv * 64) * 8;  bf16_t* lA1 = lA + (256 + wv * 64) * 8;
  bf16_t* lB0 = lB + (wv * 64) * 8;  bf16_t* lB1p = lB + (256 + wv * 64) * 8;

  f32x4_t acc[4][4] = {};
  int mrow = wm * 64 + (lane & 15);
  int ncol = wn * 64 + (lane & 15);
  int koff = (lane >> 4) * 8;

  for (int k0 = 0; k0 < Kdim; k0 += 32) {
    gload_lds16(gA0 + k0, lA0);
    gload_lds16(gA1 + k0, lA1);
    gload_lds16(gB0 + k0, lB0);
    gload_lds16(gB1 + k0, lB1p);
    __syncthreads();
    bf16x8_t af[4], bf[4];
#pragma unroll
    for (int i = 0; i < 4; ++i) {
      af[i] = *(const bf16x8_t*)&lA[(mrow + i * 16) * 32 + koff];
      bf[i] = *(const bf16x8_t*)&lB[(ncol + i * 16) * 32 + koff];
    }
#pragma unroll
    for (int mi = 0; mi < 4; ++mi)
#pragma unroll
      for (int ni = 0; ni < 4; ++ni)
        acc[mi][ni] = __builtin_amdgcn_mfma_f32_16x16x32_bf16(af[mi], bf[ni], acc[mi][ni], 0, 0, 0);
    __syncthreads();
  }

  float b2v[4];
#pragma unroll
  for (int ni = 0; ni < 4; ++ni)
    b2v[ni] = b2p[col0 + wn * 64 + ni * 16 + (lane & 15)];

#pragma unroll
  for (int mi = 0; mi < 4; ++mi)
#pragma unroll
    for (int rg = 0; rg < 4; ++rg) {
      int rl = wm * 64 + mi * 16 + ((lane >> 4) << 2) + rg;
      int grow = rowstart + rl;
      if constexpr (SCATTER) {
        int t = toklist[grow];
        float wt = wtlist[grow];
        if (t >= 0) {
          size_t ob = (size_t)t * DIMD + col0 + wn * 64 + (lane & 15);
#pragma unroll
          for (int ni = 0; ni < 4; ++ni)
            atomicAdd(&Out[ob + ni * 16], acc[mi][ni][rg] + wt * b2v[ni]);
        }
      } else {
        size_t ob = (size_t)grow * DIMD + col0 + wn * 64 + (lane & 15);
#pragma unroll
        for (int ni = 0; ni < 4; ++ni)
          Out[ob + ni * 16] = acc[mi][ni][rg] + b2v[ni];
      }
    }
}

// ---------------- host ----------------
extern "C" void kernel_launch(void* const* d_in, const int* in_sizes, int n_in,
                              void* d_out, int out_size, void* d_ws, size_t ws_size,
                              hipStream_t stream) {
  const float* x   = (const float*)d_in[0];
  const float* gw  = (const float*)d_in[1];
  const float* ew1 = (const float*)d_in[2];
  const float* eb1 = (const float*)d_in[3];
  const float* ew2 = (const float*)d_in[4];
  const float* eb2 = (const float*)d_in[5];
  const float* ew3 = (const float*)d_in[6];
  const float* eb3 = (const float*)d_in[7];
  const float* sw1 = (const float*)d_in[8];
  const float* sb1 = (const float*)d_in[9];
  const float* sw2 = (const float*)d_in[10];
  const float* sb2 = (const float*)d_in[11];
  const float* sw3 = (const float*)d_in[12];
  const float* sb3 = (const float*)d_in[13];
  float* out = (float*)d_out;

  char* ws = (char*)d_ws;
  size_t off = 0;
  auto alloc = [&](size_t bytes) -> void* {
    off = (off + 255) & ~(size_t)255;
    void* p = ws + off;
    off += bytes;
    return p;
  };

  bf16_t* xb   = (bf16_t*)alloc((size_t)TOK * DIMD * 2);
  bf16_t* ew1b = (bf16_t*)alloc((size_t)NEXP * INTERD * DIMD * 2);
  bf16_t* ew3b = (bf16_t*)alloc((size_t)NEXP * INTERD * DIMD * 2);
  bf16_t* ew2b = (bf16_t*)alloc((size_t)NEXP * DIMD * INTERD * 2);
  bf16_t* sw1b = (bf16_t*)alloc((size_t)SINTER * DIMD * 2);
  bf16_t* sw3b = (bf16_t*)alloc((size_t)SINTER * DIMD * 2);
  bf16_t* sw2b = (bf16_t*)alloc((size_t)DIMD * SINTER * 2);
  bf16_t* Hg   = (bf16_t*)alloc((size_t)CAPROWS * INTERD * 2);
  bf16_t* Hs   = (bf16_t*)alloc((size_t)TOK * SINTER * 2);
  int*   toklist = (int*)alloc(CAPROWS * 4);
  float* wtlist  = (float*)alloc(CAPROWS * 4);
  int*   counts  = (int*)alloc(64);
  int*   cursors = (int*)alloc(64);
  int*   offsets = (int*)alloc((NEXP + 1) * 4);
  int*   tile_e  = (int*)alloc(512 * 4);
  int*   tile_rs = (int*)alloc(512 * 4);
  int*   tkidx   = (int*)alloc((size_t)TOK * 4 * 4);
  float* tkwt    = (float*)alloc((size_t)TOK * 4 * 4);

  init_kernel<<<(CAPROWS + 255) / 256, 256, 0, stream>>>(toklist, wtlist, counts, cursors, tile_e, tile_rs);

  cvt_kernel<<<2048, 256, 0, stream>>>(x,   xb,   TOK * DIMD / 4);
  cvt_kernel<<<2048, 256, 0, stream>>>(ew1, ew1b, NEXP * INTERD * DIMD / 4);
  cvt_kernel<<<2048, 256, 0, stream>>>(ew3, ew3b, NEXP * INTERD * DIMD / 4);
  cvt_kernel<<<2048, 256, 0, stream>>>(ew2, ew2b, NEXP * DIMD * INTERD / 4);
  cvt_kernel<<<512,  256, 0, stream>>>(sw1, sw1b, SINTER * DIMD / 4);
  cvt_kernel<<<512,  256, 0, stream>>>(sw3, sw3b, SINTER * DIMD / 4);
  cvt_kernel<<<512,  256, 0, stream>>>(sw2, sw2b, DIMD * SINTER / 4);

  gate_kernel<<<TOK / 4, 256, 0, stream>>>(x, gw, tkidx, tkwt, counts);
  offs_kernel<<<1, 64, 0, stream>>>(counts, offsets, tile_e, tile_rs);
  scat_kernel<<<TOK * 4 / 256, 256, 0, stream>>>(tkidx, tkwt, offsets, cursors, toklist, wtlist);

  // shared expert (writes out, initializing it)
  ffn_gemm1<false><<<dim3(SINTER / 128, TOK / 128), 256, 0, stream>>>(
      xb, sw1b, sw3b, sb1, sb3, Hs, nullptr, nullptr, nullptr, nullptr, SINTER);
  ffn_gemm2<false><<<dim3(DIMD / 128, TOK / 128), 256, 0, stream>>>(
      Hs, sw2b, sb2, out, nullptr, nullptr, nullptr, nullptr, SINTER);

  // routed experts (grouped GEMM over padded token lists, scatter-add into out)
  ffn_gemm1<true><<<dim3(INTERD / 128, MAXTILES), 256, 0, stream>>>(
      xb, ew1b, ew3b, eb1, eb3, Hg, tile_e, tile_rs, toklist, wtlist, INTERD);
  ffn_gemm2<true><<<dim3(DIMD / 128, MAXTILES), 256, 0, stream>>>(
      Hg, ew2b, eb2, out, tile_e, tile_rs, toklist, wtlist, INTERD);
}

// Round 2
// 653.535 us; speedup vs baseline: 1.6429x; 1.6429x over previous
//
#include <hip/hip_runtime.h>
#include <cstdint>
#include <cstddef>

#define TOK     8192
#define DIMD    1024
#define INTERD  1024
#define NEXP    16
#define SINTER  2048
#define CAPROWS 34816   // 32768 + 16*128 padding capacity
#define MAXTILES 272    // sum ceil(cnt_e/128) <= 256 + 16
#define HBLK    32      // histogram/scatter blocks

typedef __bf16 bf16_t;
typedef __bf16 bf16x8_t __attribute__((ext_vector_type(8)));
typedef __bf16 bf16x4_t __attribute__((ext_vector_type(4)));
typedef float  f32x4_t  __attribute__((ext_vector_type(4)));

// async global->LDS, 16B per lane; LDS dest is wave-uniform base + lane*16
__device__ __forceinline__ void gload_lds16(const bf16_t* g, bf16_t* l) {
  __builtin_amdgcn_global_load_lds((const __attribute__((address_space(1))) void*)g,
                                   (__attribute__((address_space(3))) void*)l,
                                   16, 0, 0);
}

// ---------------- init: pad lists, clear tile table ----------------
__global__ void init_kernel(int* toklist, float* wtlist, int* tile_e, int* tile_rs) {
  int i = blockIdx.x * blockDim.x + threadIdx.x;
  if (i < CAPROWS) { toklist[i] = -1; wtlist[i] = 0.0f; }
  if (i < 512)     { tile_e[i] = -1; tile_rs[i] = 0; }
}

// ---------------- fp32 -> bf16 conversion ----------------
__global__ void cvt_kernel(const float* __restrict__ in, bf16_t* __restrict__ out, int n4) {
  int stride = gridDim.x * blockDim.x;
  for (int i = blockIdx.x * blockDim.x + threadIdx.x; i < n4; i += stride) {
    float4 v = ((const float4*)in)[i];
    bf16x4_t o;
    o[0] = (bf16_t)v.x; o[1] = (bf16_t)v.y; o[2] = (bf16_t)v.z; o[3] = (bf16_t)v.w;
    ((bf16x4_t*)out)[i] = o;
  }
}

// ---------------- gate: scores -> softmax -> top4 (fp32, one wave/token) ----------------
__global__ __launch_bounds__(256)
void gate_kernel(const float* __restrict__ x, const float* __restrict__ gw,
                 int* __restrict__ tkidx, float* __restrict__ tkwt) {
  int wv = threadIdx.x >> 6, lane = threadIdx.x & 63;
  int t = blockIdx.x * 4 + wv;
  const float4* xp = (const float4*)(x + (size_t)t * DIMD + lane * 16);
  float4 xv[4];
#pragma unroll
  for (int i = 0; i < 4; ++i) xv[i] = xp[i];
  float sc[NEXP];
#pragma unroll
  for (int e = 0; e < NEXP; ++e) {
    const float4* wp = (const float4*)(gw + (size_t)e * DIMD + lane * 16);
    float s = 0.0f;
#pragma unroll
    for (int i = 0; i < 4; ++i) {
      float4 w = wp[i];
      s += xv[i].x * w.x + xv[i].y * w.y + xv[i].z * w.z + xv[i].w * w.w;
    }
    sc[e] = s;
  }
#pragma unroll
  for (int off = 32; off > 0; off >>= 1)
#pragma unroll
    for (int e = 0; e < NEXP; ++e)
      sc[e] += __shfl_xor(sc[e], off, 64);
  if (lane == 0) {
    float m = sc[0];
#pragma unroll
    for (int e = 1; e < NEXP; ++e) m = fmaxf(m, sc[e]);
    float p[NEXP], s = 0.0f;
#pragma unroll
    for (int e = 0; e < NEXP; ++e) { p[e] = __expf(sc[e] - m); s += p[e]; }
    float inv = 1.0f / s;
    unsigned used = 0;
    for (int k = 0; k < 4; ++k) {
      int best = 0; float bv = -1.0f;
#pragma unroll
      for (int e = 0; e < NEXP; ++e)
        if (!((used >> e) & 1u) && p[e] > bv) { bv = p[e]; best = e; }
      used |= 1u << best;
      tkidx[t * 4 + k] = best;
      tkwt[t * 4 + k] = bv * inv;
    }
  }
}

// ---------------- per-block histogram (no global atomics) ----------------
__global__ __launch_bounds__(256)
void hist_kernel(const int* __restrict__ tkidx, int* __restrict__ blkhist) {
  __shared__ int h[NEXP];
  if (threadIdx.x < NEXP) h[threadIdx.x] = 0;
  __syncthreads();
  int4 v = ((const int4*)tkidx)[blockIdx.x * 256 + threadIdx.x];
  atomicAdd(&h[v.x], 1);
  atomicAdd(&h[v.y], 1);
  atomicAdd(&h[v.z], 1);
  atomicAdd(&h[v.w], 1);
  __syncthreads();
  if (threadIdx.x < NEXP) blkhist[blockIdx.x * NEXP + threadIdx.x] = h[threadIdx.x];
}

// ---------------- offsets + tile table + per-block scatter bases ----------------
__global__ void offs_kernel(const int* __restrict__ blkhist, int* __restrict__ offsets,
                            int* __restrict__ blkbase,
                            int* __restrict__ tile_e, int* __restrict__ tile_rs) {
  if (threadIdx.x != 0 || blockIdx.x != 0) return;
  int counts[NEXP];
  for (int e = 0; e < NEXP; ++e) {
    int s = 0;
    for (int b = 0; b < HBLK; ++b) s += blkhist[b * NEXP + e];
    counts[e] = s;
  }
  int off = 0, nt = 0;
  for (int e = 0; e < NEXP; ++e) {
    offsets[e] = off;
    int c = counts[e];
    int ntile = (c + 127) >> 7;
    for (int i = 0; i < ntile; ++i) { tile_e[nt] = e; tile_rs[nt] = off + (i << 7); ++nt; }
    off += ntile << 7;
  }
  offsets[NEXP] = off;
  for (int e = 0; e < NEXP; ++e) {
    int base = offsets[e];
    for (int b = 0; b < HBLK; ++b) {
      blkbase[b * NEXP + e] = base;
      base += blkhist[b * NEXP + e];
    }
  }
}

// ---------------- scatter tokens into per-expert lists (LDS cursors only) ----------------
__global__ __launch_bounds__(256)
void scat_kernel(const int* __restrict__ tkidx, const float* __restrict__ tkwt,
                 const int* __restrict__ blkbase,
                 int* __restrict__ toklist, float* __restrict__ wtlist) {
  __shared__ int cur[NEXP];
  if (threadIdx.x < NEXP) cur[threadIdx.x] = blkbase[blockIdx.x * NEXP + threadIdx.x];
  __syncthreads();
  int idx = blockIdx.x * 256 + threadIdx.x;      // token index within [0,8192)
  int4 v = ((const int4*)tkidx)[idx];
  float4 w = ((const float4*)tkwt)[idx];
  int t = idx;                                    // 4 entries per token, aligned
  int p0 = atomicAdd(&cur[v.x], 1);
  toklist[p0] = t; wtlist[p0] = w.x;
  int p1 = atomicAdd(&cur[v.y], 1);
  toklist[p1] = t; wtlist[p1] = w.y;
  int p2 = atomicAdd(&cur[v.z], 1);
  toklist[p2] = t; wtlist[p2] = w.z;
  int p3 = atomicAdd(&cur[v.w], 1);
  toklist[p3] = t; wtlist[p3] = w.w;
}

// ---------------- dual GEMM1: H = silu(X*W1^T+b1)*(X*W3^T+b3)*wt ----------------
// 128x128 tile, BK=32, 4 waves each 64x64 (4x4 frags), global_load_lds staging.
template <bool GATHER>
__global__ __launch_bounds__(256, 2)
void ffn_gemm1(const bf16_t* __restrict__ Xb,
               const bf16_t* __restrict__ W1b, const bf16_t* __restrict__ W3b,
               const float* __restrict__ B1b, const float* __restrict__ B3b,
               bf16_t* __restrict__ H,
               const int* __restrict__ tile_e, const int* __restrict__ tile_rs,
               const int* __restrict__ toklist, const float* __restrict__ wtlist,
               int Ncols) {
  __shared__ __align__(16) bf16_t lA[128 * 32];
  __shared__ __align__(16) bf16_t lB1[128 * 32];
  __shared__ __align__(16) bf16_t lB3[128 * 32];

  int rowstart;
  const bf16_t *W1, *W3;
  const float *b1p, *b3p;
  if constexpr (GATHER) {
    int e = tile_e[blockIdx.y];
    if (e < 0) return;
    rowstart = tile_rs[blockIdx.y];
    W1 = W1b + (size_t)e * INTERD * DIMD;
    W3 = W3b + (size_t)e * INTERD * DIMD;
    b1p = B1b + e * INTERD;
    b3p = B3b + e * INTERD;
  } else {
    rowstart = blockIdx.y * 128;
    W1 = W1b; W3 = W3b; b1p = B1b; b3p = B3b;
  }
  int col0 = blockIdx.x * 128;
  int tid = threadIdx.x, lane = tid & 63, wv = tid >> 6;
  int wm = wv >> 1, wn = wv & 1;

  // staging: chunk c covers LDS bytes [c*16,+16) = row c>>2, k-elems [(c&3)*8,+8)
  int r0 = tid >> 2, r1 = r0 + 64, kc = (tid & 3) * 8;
  int tA0, tA1;
  if constexpr (GATHER) {
    tA0 = toklist[rowstart + r0]; if (tA0 < 0) tA0 = 0;
    tA1 = toklist[rowstart + r1]; if (tA1 < 0) tA1 = 0;
  } else { tA0 = rowstart + r0; tA1 = rowstart + r1; }
  const bf16_t* gA0 = Xb + (size_t)tA0 * DIMD + kc;
  const bf16_t* gA1 = Xb + (size_t)tA1 * DIMD + kc;
  const bf16_t* gB10 = W1 + (size_t)(col0 + r0) * DIMD + kc;
  const bf16_t* gB11 = W1 + (size_t)(col0 + r1) * DIMD + kc;
  const bf16_t* gB30 = W3 + (size_t)(col0 + r0) * DIMD + kc;
  const bf16_t* gB31 = W3 + (size_t)(col0 + r1) * DIMD + kc;
  bf16_t* lA0 = lA + (wv * 64) * 8;        bf16_t* lA1 = lA + (256 + wv * 64) * 8;
  bf16_t* lB10 = lB1 + (wv * 64) * 8;      bf16_t* lB11 = lB1 + (256 + wv * 64) * 8;
  bf16_t* lB30 = lB3 + (wv * 64) * 8;      bf16_t* lB31 = lB3 + (256 + wv * 64) * 8;

  f32x4_t acc1[4][4] = {};
  f32x4_t acc3[4][4] = {};

  int mrow = wm * 64 + (lane & 15);
  int ncol = wn * 64 + (lane & 15);
  int koff = (lane >> 4) * 8;

  for (int k0 = 0; k0 < DIMD; k0 += 32) {
    gload_lds16(gA0 + k0, lA0);
    gload_lds16(gA1 + k0, lA1);
    gload_lds16(gB10 + k0, lB10);
    gload_lds16(gB11 + k0, lB11);
    gload_lds16(gB30 + k0, lB30);
    gload_lds16(gB31 + k0, lB31);
    __syncthreads();
    bf16x8_t af[4], b1f[4], b3f[4];
#pragma unroll
    for (int i = 0; i < 4; ++i) {
      af[i]  = *(const bf16x8_t*)&lA [(mrow + i * 16) * 32 + koff];
      b1f[i] = *(const bf16x8_t*)&lB1[(ncol + i * 16) * 32 + koff];
      b3f[i] = *(const bf16x8_t*)&lB3[(ncol + i * 16) * 32 + koff];
    }
#pragma unroll
    for (int mi = 0; mi < 4; ++mi)
#pragma unroll
      for (int ni = 0; ni < 4; ++ni) {
        acc1[mi][ni] = __builtin_amdgcn_mfma_f32_16x16x32_bf16(af[mi], b1f[ni], acc1[mi][ni], 0, 0, 0);
        acc3[mi][ni] = __builtin_amdgcn_mfma_f32_16x16x32_bf16(af[mi], b3f[ni], acc3[mi][ni], 0, 0, 0);
      }
    __syncthreads();
  }

  float bias1[4], bias3[4];
#pragma unroll
  for (int ni = 0; ni < 4; ++ni) {
    int cg = col0 + wn * 64 + ni * 16 + (lane & 15);
    bias1[ni] = b1p[cg];
    bias3[ni] = b3p[cg];
  }
#pragma unroll
  for (int mi = 0; mi < 4; ++mi)
#pragma unroll
    for (int rg = 0; rg < 4; ++rg) {
      int rl = wm * 64 + mi * 16 + ((lane >> 4) << 2) + rg;  // C/D: row=(lane>>4)*4+reg
      int grow = rowstart + rl;
      float wt = 1.0f;
      if constexpr (GATHER) wt = wtlist[grow];
      size_t hbase = (size_t)grow * Ncols + col0 + wn * 64 + (lane & 15);
#pragma unroll
      for (int ni = 0; ni < 4; ++ni) {
        float v1 = acc1[mi][ni][rg] + bias1[ni];
        float v3 = acc3[mi][ni][rg] + bias3[ni];
        float sg = v1 / (1.0f + __expf(-v1));
        H[hbase + ni * 16] = (bf16_t)(sg * v3 * wt);
      }
    }
}

// ---------------- GEMM2: out = H*W2^T (+ wt*b2 scatter-add | + b2 write) ----------------
template <bool SCATTER>
__global__ __launch_bounds__(256, 2)
void ffn_gemm2(const bf16_t* __restrict__ Hin, const bf16_t* __restrict__ W2b,
               const float* __restrict__ B2b, float* __restrict__ Out,
               const int* __restrict__ tile_e, const int* __restrict__ tile_rs,
               const int* __restrict__ toklist, const float* __restrict__ wtlist,
               int Kdim) {
  __shared__ __align__(16) bf16_t lA[128 * 32];
  __shared__ __align__(16) bf16_t lB[128 * 32];

  int rowstart;
  const bf16_t* W2;
  const float* b2p;
  if constexpr (SCATTER) {
    int e = tile_e[blockIdx.y];
    if (e < 0) return;
    rowstart = tile_rs[blockIdx.y];
    W2 = W2b + (size_t)e * DIMD * INTERD;
    b2p = B2b + e * DIMD;
  } else {
    rowstart = blockIdx.y * 128;
    W2 = W2b; b2p = B2b;
  }
  int col0 = blockIdx.x * 128;
  int tid = threadIdx.x, lane = tid & 63, wv = tid >> 6;
  int wm = wv >> 1, wn = wv & 1;

  int r0 = tid >> 2, r1 = r0 + 64, kc = (tid & 3) * 8;
  const bf16_t* gA0 = Hin + (size_t)(rowstart + r0) * Kdim + kc;
  const bf16_t* gA1 = Hin + (size_t)(rowstart + r1) * Kdim + kc;
  const bf16_t* gB0 = W2 + (size_t)(col0 + r0) * Kdim + kc;
  const bf16_t* gB1 = W2 + (size_t)(col0 + r1) * Kdim + kc;
  bf16_t* lA0 = lA + (wv * 64) * 8;  bf16_t* lA1 = lA + (256 + wv * 64) * 8;
  bf16_t* lB0 = lB + (wv * 64) * 8;  bf16_t* lB1p = lB + (256 + wv * 64) * 8;

  f32x4_t acc[4][4] = {};
  int mrow = wm * 64 + (lane & 15);
  int ncol = wn * 64 + (lane & 15);
  int koff = (lane >> 4) * 8;

  for (int k0 = 0; k0 < Kdim; k0 += 32) {
    gload_lds16(gA0 + k0, lA0);
    gload_lds16(gA1 + k0, lA1);
    gload_lds16(gB0 + k0, lB0);
    gload_lds16(gB1 + k0, lB1p);
    __syncthreads();
    bf16x8_t af[4], bf[4];
#pragma unroll
    for (int i = 0; i < 4; ++i) {
      af[i] = *(const bf16x8_t*)&lA[(mrow + i * 16) * 32 + koff];
      bf[i] = *(const bf16x8_t*)&lB[(ncol + i * 16) * 32 + koff];
    }
#pragma unroll
    for (int mi = 0; mi < 4; ++mi)
#pragma unroll
      for (int ni = 0; ni < 4; ++ni)
        acc[mi][ni] = __builtin_amdgcn_mfma_f32_16x16x32_bf16(af[mi], bf[ni], acc[mi][ni], 0, 0, 0);
    __syncthreads();
  }

  float b2v[4];
#pragma unroll
  for (int ni = 0; ni < 4; ++ni)
    b2v[ni] = b2p[col0 + wn * 64 + ni * 16 + (lane & 15)];

#pragma unroll
  for (int mi = 0; mi < 4; ++mi)
#pragma unroll
    for (int rg = 0; rg < 4; ++rg) {
      int rl = wm * 64 + mi * 16 + ((lane >> 4) << 2) + rg;
      int grow = rowstart + rl;
      if constexpr (SCATTER) {
        int t = toklist[grow];
        float wt = wtlist[grow];
        if (t >= 0) {
          size_t ob = (size_t)t * DIMD + col0 + wn * 64 + (lane & 15);
#pragma unroll
          for (int ni = 0; ni < 4; ++ni)
            atomicAdd(&Out[ob + ni * 16], acc[mi][ni][rg] + wt * b2v[ni]);
        }
      } else {
        size_t ob = (size_t)grow * DIMD + col0 + wn * 64 + (lane & 15);
#pragma unroll
        for (int ni = 0; ni < 4; ++ni)
          Out[ob + ni * 16] = acc[mi][ni][rg] + b2v[ni];
      }
    }
}

// ---------------- host ----------------
extern "C" void kernel_launch(void* const* d_in, const int* in_sizes, int n_in,
                              void* d_out, int out_size, void* d_ws, size_t ws_size,
                              hipStream_t stream) {
  const float* x   = (const float*)d_in[0];
  const float* gw  = (const float*)d_in[1];
  const float* ew1 = (const float*)d_in[2];
  const float* eb1 = (const float*)d_in[3];
  const float* ew2 = (const float*)d_in[4];
  const float* eb2 = (const float*)d_in[5];
  const float* ew3 = (const float*)d_in[6];
  const float* eb3 = (const float*)d_in[7];
  const float* sw1 = (const float*)d_in[8];
  const float* sb1 = (const float*)d_in[9];
  const float* sw2 = (const float*)d_in[10];
  const float* sb2 = (const float*)d_in[11];
  const float* sw3 = (const float*)d_in[12];
  const float* sb3 = (const float*)d_in[13];
  float* out = (float*)d_out;

  char* ws = (char*)d_ws;
  size_t off = 0;
  auto alloc = [&](size_t bytes) -> void* {
    off = (off + 255) & ~(size_t)255;
    void* p = ws + off;
    off += bytes;
    return p;
  };

  bf16_t* xb   = (bf16_t*)alloc((size_t)TOK * DIMD * 2);
  bf16_t* ew1b = (bf16_t*)alloc((size_t)NEXP * INTERD * DIMD * 2);
  bf16_t* ew3b = (bf16_t*)alloc((size_t)NEXP * INTERD * DIMD * 2);
  bf16_t* ew2b = (bf16_t*)alloc((size_t)NEXP * DIMD * INTERD * 2);
  bf16_t* sw1b = (bf16_t*)alloc((size_t)SINTER * DIMD * 2);
  bf16_t* sw3b = (bf16_t*)alloc((size_t)SINTER * DIMD * 2);
  bf16_t* sw2b = (bf16_t*)alloc((size_t)DIMD * SINTER * 2);
  bf16_t* Hg   = (bf16_t*)alloc((size_t)CAPROWS * INTERD * 2);
  bf16_t* Hs   = (bf16_t*)alloc((size_t)TOK * SINTER * 2);
  int*   toklist = (int*)alloc(CAPROWS * 4);
  float* wtlist  = (float*)alloc(CAPROWS * 4);
  int*   offsets = (int*)alloc((NEXP + 1) * 4);
  int*   blkhist = (int*)alloc(HBLK * NEXP * 4);
  int*   blkbase = (int*)alloc(HBLK * NEXP * 4);
  int*   tile_e  = (int*)alloc(512 * 4);
  int*   tile_rs = (int*)alloc(512 * 4);
  int*   tkidx   = (int*)alloc((size_t)TOK * 4 * 4);
  float* tkwt    = (float*)alloc((size_t)TOK * 4 * 4);

  init_kernel<<<(CAPROWS + 255) / 256, 256, 0, stream>>>(toklist, wtlist, tile_e, tile_rs);

  cvt_kernel<<<2048, 256, 0, stream>>>(x,   xb,   TOK * DIMD / 4);
  cvt_kernel<<<2048, 256, 0, stream>>>(ew1, ew1b, NEXP * INTERD * DIMD / 4);
  cvt_kernel<<<2048, 256, 0, stream>>>(ew3, ew3b, NEXP * INTERD * DIMD / 4);
  cvt_kernel<<<2048, 256, 0, stream>>>(ew2, ew2b, NEXP * DIMD * INTERD / 4);
  cvt_kernel<<<512,  256, 0, stream>>>(sw1, sw1b, SINTER * DIMD / 4);
  cvt_kernel<<<512,  256, 0, stream>>>(sw3, sw3b, SINTER * DIMD / 4);
  cvt_kernel<<<512,  256, 0, stream>>>(sw2, sw2b, DIMD * SINTER / 4);

  gate_kernel<<<TOK / 4, 256, 0, stream>>>(x, gw, tkidx, tkwt);
  hist_kernel<<<HBLK, 256, 0, stream>>>(tkidx, blkhist);
  offs_kernel<<<1, 64, 0, stream>>>(blkhist, offsets, blkbase, tile_e, tile_rs);
  scat_kernel<<<HBLK, 256, 0, stream>>>(tkidx, tkwt, blkbase, toklist, wtlist);

  // shared expert (writes out, initializing it)
  ffn_gemm1<false><<<dim3(SINTER / 128, TOK / 128), 256, 0, stream>>>(
      xb, sw1b, sw3b, sb1, sb3, Hs, nullptr, nullptr, nullptr, nullptr, SINTER);
  ffn_gemm2<false><<<dim3(DIMD / 128, TOK / 128), 256, 0, stream>>>(
      Hs, sw2b, sb2, out, nullptr, nullptr, nullptr, nullptr, SINTER);

  // routed experts (grouped GEMM over padded token lists, scatter-add into out)
  ffn_gemm1<true><<<dim3(INTERD / 128, MAXTILES), 256, 0, stream>>>(
      xb, ew1b, ew3b, eb1, eb3, Hg, tile_e, tile_rs, toklist, wtlist, INTERD);
  ffn_gemm2<true><<<dim3(DIMD / 128, MAXTILES), 256, 0, stream>>>(
      Hg, ew2b, eb2, out, tile_e, tile_rs, toklist, wtlist, INTERD);
}